// Round 3
// baseline (289.125 us; speedup 1.0000x reference)
//
#include <hip/hip_runtime.h>
#include <stdint.h>
#include <stddef.h>

#define NB 2
#define NT 4096
#define NC 768
#define NH 12
#define ND 64

typedef unsigned short u16;
typedef __attribute__((ext_vector_type(4))) float f32x4;
typedef __attribute__((ext_vector_type(16))) float f32x16;
typedef __attribute__((ext_vector_type(8))) unsigned short u16x8;
typedef __attribute__((ext_vector_type(4))) unsigned short u16x4;
typedef __attribute__((ext_vector_type(8))) __bf16 bf16x8;
typedef __attribute__((ext_vector_type(4))) unsigned int u32x4;

typedef __attribute__((address_space(1))) const unsigned int gu32;
typedef __attribute__((address_space(3))) unsigned int lu32;

__device__ __forceinline__ u16 f2bf(float f) {
  uint32_t u = __builtin_bit_cast(uint32_t, f);
  u += 0x7FFFu + ((u >> 16) & 1u);   // RTNE
  return (u16)(u >> 16);
}
__device__ __forceinline__ bf16x8 asbf(u16x8 v) { return __builtin_bit_cast(bf16x8, v); }

// pack two f32 -> two bf16, round-half-up: 3 VALU
__device__ __forceinline__ uint32_t pkbf(float a, float b) {
  uint32_t ua = __builtin_bit_cast(uint32_t, a) + 0x8000u;
  uint32_t ub = __builtin_bit_cast(uint32_t, b) + 0x8000u;
  return __builtin_amdgcn_perm(ub, ua, 0x07060302u);
}
// truncating pack (P only; numerator/denominator stay consistent): 1 VALU
__device__ __forceinline__ uint32_t pktr(float a, float b) {
  return __builtin_amdgcn_perm(__builtin_bit_cast(uint32_t, b),
                               __builtin_bit_cast(uint32_t, a), 0x07060302u);
}

// ---------------- cast fp32 -> bf16 ----------------
__global__ void k_cast(const float* __restrict__ in, u16* __restrict__ out, int n4) {
  int i = blockIdx.x * blockDim.x + threadIdx.x;
  if (i < n4) {
    f32x4 v = ((const f32x4*)in)[i];
    u16x4 o;
    o[0] = f2bf(v[0]); o[1] = f2bf(v[1]); o[2] = f2bf(v[2]); o[3] = f2bf(v[3]);
    ((u16x4*)out)[i] = o;
  }
}

// -------- transpose + cast --------
__global__ void k_transpose(const float* __restrict__ in, u16* __restrict__ out,
                            int R, int Cn) {
  __shared__ float tile[32][33];
  int c0 = blockIdx.x * 32, r0 = blockIdx.y * 32;
  int tx = threadIdx.x & 31, ty = threadIdx.x >> 5;
  for (int i = ty; i < 32; i += 8)
    tile[i][tx] = in[(size_t)(r0 + i) * Cn + c0 + tx];
  __syncthreads();
  for (int i = ty; i < 32; i += 8)
    out[(size_t)(c0 + i) * R + r0 + tx] = f2bf(tile[tx][i]);
}

// -------- GEMM: C[M,N] = A[M,K] * Bt[N,K]^T --------
template <int EPI>
__global__ __launch_bounds__(256, 2)
void k_gemm_bt(const u16* __restrict__ A, const u16* __restrict__ Bt,
               int M, int N, int K,
               u16* __restrict__ o0, u16* __restrict__ o1, u16* __restrict__ o2,
               float* __restrict__ of) {
  __shared__ u16 As[128 * 40];
  __shared__ u16 Bs[128 * 40];
  const int tid = threadIdx.x;
  const int wave = tid >> 6, lane = tid & 63, quad = lane >> 4, lc = lane & 15;
  const int wm = (wave & 1) * 64, wn = (wave >> 1) * 64;
  const int bm = blockIdx.y * 128, bn = blockIdx.x * 128;

  const int sr = tid >> 2;
  const int sc8 = (tid & 3) * 8;
  const u16* ap0 = A + (size_t)(bm + sr) * K + sc8;
  const u16* ap1 = A + (size_t)(bm + 64 + sr) * K + sc8;
  const u16* bp0 = Bt + (size_t)(bn + sr) * K + sc8;
  const u16* bp1 = Bt + (size_t)(bn + 64 + sr) * K + sc8;
  u16* asl0 = &As[sr * 40 + sc8];
  u16* asl1 = &As[(64 + sr) * 40 + sc8];
  u16* bsl0 = &Bs[sr * 40 + sc8];
  u16* bsl1 = &Bs[(64 + sr) * 40 + sc8];

  f32x4 zv = {0.f, 0.f, 0.f, 0.f};
  f32x4 acc[4][4];
#pragma unroll
  for (int i = 0; i < 4; ++i)
#pragma unroll
    for (int j = 0; j < 4; ++j) acc[i][j] = zv;

  for (int k0 = 0; k0 < K; k0 += 32) {
    u16x8 a0 = *(const u16x8*)(ap0 + k0);
    u16x8 a1 = *(const u16x8*)(ap1 + k0);
    u16x8 b0 = *(const u16x8*)(bp0 + k0);
    u16x8 b1 = *(const u16x8*)(bp1 + k0);
    __syncthreads();
    *(u16x8*)asl0 = a0;
    *(u16x8*)asl1 = a1;
    *(u16x8*)bsl0 = b0;
    *(u16x8*)bsl1 = b1;
    __syncthreads();

    bf16x8 af[4], bfv[4];
#pragma unroll
    for (int mi = 0; mi < 4; ++mi)
      af[mi] = asbf(*(const u16x8*)&As[(wm + mi * 16 + lc) * 40 + quad * 8]);
#pragma unroll
    for (int ni = 0; ni < 4; ++ni)
      bfv[ni] = asbf(*(const u16x8*)&Bs[(wn + ni * 16 + lc) * 40 + quad * 8]);
#pragma unroll
    for (int mi = 0; mi < 4; ++mi)
#pragma unroll
      for (int ni = 0; ni < 4; ++ni)
        acc[mi][ni] = __builtin_amdgcn_mfma_f32_16x16x32_bf16(af[mi], bfv[ni],
                                                              acc[mi][ni], 0, 0, 0);
  }

  const int mrow0 = bm + wm + quad * 4;
#pragma unroll
  for (int mi = 0; mi < 4; ++mi) {
    const int mbase = mrow0 + mi * 16;
#pragma unroll
    for (int ni = 0; ni < 4; ++ni) {
      const int n = bn + wn + ni * 16 + lc;
      if (EPI == 0) {
#pragma unroll
        for (int r = 0; r < 4; ++r)
          of[(size_t)(mbase + r) * N + n] = acc[mi][ni][r];
      } else {
        const int sect = n / NC;          // 0=q 1=k 2=v
        const int wn2 = n - sect * NC;
        const int h = wn2 >> 6, d = wn2 & 63;
        const int b = mbase >> 12;
        const int t = mbase & (NT - 1);
        const float sc = (sect == 0) ? 0.18033688011112042f : 1.0f;  // log2e/8
        if (sect == 2) {
          u16x4 pk;
#pragma unroll
          for (int r = 0; r < 4; ++r) pk[r] = f2bf(acc[mi][ni][r]);
          *(u16x4*)&o2[((size_t)(b * NH + h) * ND + d) * NT + t] = pk;
        } else {
          u16* dst = (sect == 0) ? o0 : o1;
#pragma unroll
          for (int r = 0; r < 4; ++r)
            dst[((size_t)(b * NH + h) * NT + (t + r)) * ND + d] =
                f2bf(acc[mi][ni][r] * sc);
        }
      }
    }
  }
}

// ============ flash attention v3: 128q tiles, DMA dbuf, frag sharing =======
// Grid 768 = 24 bh x 32 j-tiles (128 q rows) = exactly 3 blocks/CU.
// j hashed (bijective per bh) so both contiguous and stride-256 CU-triples get
// near-uniform total work despite the causal 16:1 per-block spread.
// 4 waves = (qh: 64q) x (th: 32t). Each wave holds TWO 32-q B-operand sets and
// shares every K/V fragment read across both -> 4 ds_reads feed 8 MFMAs (2x
// better than round 2). Staging via global_load_lds (16B) into a double
// buffer: linear LDS dest + inverse-XOR-swizzled per-lane SOURCE address
// (T21), counted s_waitcnt vmcnt(4) + raw s_barrier so next-tile DMAs stay in
// flight across the barrier (no drain-to-0 in the loop).
// P never touches LDS (pktr + permlane32_swap, proven r1/r2); denominator =
// in-lane truncated-exp sum (bf16-consistent) + shfl_xor + cross-th LDS park.

template <bool MSK>
__device__ __forceinline__ void softpackT(const f32x16& s, int l31, int l5,
                                          float& sl, bf16x8* pf) {
  float e[16];
#pragma unroll
  for (int r = 0; r < 16; ++r) {
    float v = s[r];
    if (MSK) {
      int tl = (r & 3) + 8 * (r >> 2) + 4 * l5;   // 32x32 C-layout row (t)
      v = (tl > l31) ? -1e30f : v;
    }
    e[r] = exp2f(v);
    sl += __builtin_bit_cast(float,
          __builtin_bit_cast(uint32_t, e[r]) & 0xFFFF0000u);
  }
  uint32_t wv[8];
#pragma unroll
  for (int i = 0; i < 8; ++i) wv[i] = pktr(e[2 * i], e[2 * i + 1]);
#pragma unroll
  for (int g = 0; g < 2; ++g) {
    auto r0 = __builtin_amdgcn_permlane32_swap(wv[g * 4 + 0], wv[g * 4 + 2], false, false);
    auto r1 = __builtin_amdgcn_permlane32_swap(wv[g * 4 + 1], wv[g * 4 + 3], false, false);
    u32x4 f = {r0[0], r1[0], r0[1], r1[1]};
    pf[g] = __builtin_bit_cast(bf16x8, f);
  }
}

#define GLDS(gsrc, ldst) __builtin_amdgcn_global_load_lds( \
    (gu32*)(gsrc), (lu32*)(ldst), 16, 0, 0)

__global__ __launch_bounds__(256, 3)
void k_attn(const u16* __restrict__ Q, const u16* __restrict__ K,
            const u16* __restrict__ Vt, u16* __restrict__ Y) {
  // dbuf staging: buf p at RAW[p*8192]: K tile [64t][64d] elems 0..4095,
  // V^T tile [64d][64t] elems 4096..8191. Epilogue park overlays (128x65 f32).
  __shared__ u16 RAW[2 * 8192 + 768];
  __shared__ float PLs[128];
  const int tid = threadIdx.x;
  const int lane = tid & 63, wave = tid >> 6;
  const int l5 = lane >> 5, l31 = lane & 31;
  const int qh = wave & 1, th = wave >> 1;
  const int o_ = blockIdx.x;
  const int bh = o_ >> 5;
  const int jj = ((((o_ & 31) + bh) & 31) * 11) & 31;   // balance hash
  const int b = bh / NH, h = bh - b * NH;
  const u16* __restrict__ Qb = Q + (size_t)bh * NT * ND;
  const u16* __restrict__ Kb = K + (size_t)bh * NT * ND;
  const u16* __restrict__ Vb = Vt + (size_t)bh * (size_t)ND * NT;

  const int Qb0 = jj * 128;
  const int qu0 = 4 * jj + 2 * qh;      // 32-row unit index of subhalf A
  const int ntau = 2 * jj + 2;

  // Q as B-operand frags (col q = l31, k(d) = ks*16 + l5*8 + j); log2e/8 folded
  const int qgA = Qb0 + qh * 64 + l31;
  const int qgB = qgA + 32;
  bf16x8 bqA[4], bqB[4];
#pragma unroll
  for (int ks = 0; ks < 4; ++ks) {
    bqA[ks] = asbf(*(const u16x8*)(Qb + (size_t)qgA * ND + ks * 16 + l5 * 8));
    bqB[ks] = asbf(*(const u16x8*)(Qb + (size_t)qgB * ND + ks * 16 + l5 * 8));
  }

  f32x16 Zv;
#pragma unroll
  for (int i = 0; i < 16; ++i) Zv[i] = 0.f;
  f32x16 oA0 = Zv, oA1 = Zv, oB0 = Zv, oB1 = Zv;   // O^T partials, d-halves
  float slA = 0.f, slB = 0.f;

  // DMA staging: wave w stages LDS rows [16w,16w+16) of K and of V.
  // LDS layout element off = row*64 + (g ^ (row&7))*8 ; DMA writes linear
  // (lane c -> row +c/8, granule c%8), so the SOURCE granule is pre-swizzled.
  const int lr = lane >> 3;                       // 0..7
  const int gsw = ((lane & 7) ^ lr) * 8;          // inverse-swizzled granule
  const int r0w = wave * 16;
  const u16* gk0 = Kb + (size_t)(r0w + lr) * ND + gsw;       // + t0*ND
  const u16* gk1 = gk0 + (size_t)8 * ND;
  const u16* gv0 = Vb + (size_t)(r0w + lr) * NT + gsw;       // + t0
  const u16* gv1 = gv0 + (size_t)8 * NT;
  u16* lk0 = &RAW[r0w * 64];
  u16* lv0 = &RAW[4096 + r0w * 64];

  // frag read offsets (elements) within a buffer
  int qfro[4];
#pragma unroll
  for (int ks = 0; ks < 4; ++ks)
    qfro[ks] = (th * 32 + l31) * 64 + (((ks * 2 + l5) ^ (l31 & 7)) * 8);
  int vfro[2];
#pragma unroll
  for (int kp = 0; kp < 2; ++kp)
    vfro[kp] = 4096 + l31 * 64 + (((4 * th + 2 * kp + l5) ^ (l31 & 7)) * 8);

  // prologue: DMA tile 0 into buf 0
  GLDS(gk0, lk0);
  GLDS(gk1, lk0 + 512);
  GLDS(gv0, lv0);
  GLDS(gv1, lv0 + 512);

#pragma unroll 1
  for (int tau = 0; tau < ntau; ++tau) {
    const int p = tau & 1;
    if (tau + 1 < ntau) {               // issue next tile into other buf
      const int tn = (tau + 1) * 64;
      const int bo = (p ^ 1) * 8192;
      GLDS(gk0 + (size_t)tn * ND, lk0 + bo);
      GLDS(gk1 + (size_t)tn * ND, lk0 + bo + 512);
      GLDS(gv0 + tn, lv0 + bo);
      GLDS(gv1 + tn, lv0 + bo + 512);
      asm volatile("s_waitcnt vmcnt(4)" ::: "memory");  // current tile done
    } else {
      asm volatile("s_waitcnt vmcnt(0)" ::: "memory");
    }
    __builtin_amdgcn_s_barrier();       // all waves' tile-tau DMA complete

    const int u = 2 * tau + th;
    const int d0 = qu0 - u;             // s=0: >0 full, ==0 diag, <0 skip
    if (d0 >= -1) {                     // wave has work (s=1 active)
      const bool act0 = (d0 >= 0);
      const u16* bufp = &RAW[p * 8192];

      // ---- S^T = K Q^T, K frag shared across both q-subhalves ----
      f32x16 sA = Zv, sB = Zv;
#pragma unroll
      for (int ks = 0; ks < 4; ++ks) {
        bf16x8 kf = asbf(*(const u16x8*)&bufp[qfro[ks]]);
        if (act0)
          sA = __builtin_amdgcn_mfma_f32_32x32x16_bf16(kf, bqA[ks], sA, 0, 0, 0);
        sB = __builtin_amdgcn_mfma_f32_32x32x16_bf16(kf, bqB[ks], sB, 0, 0, 0);
      }

      // ---- softmax numerators in-register ----
      bf16x8 pA[2], pB[2];
      if (act0) {
        if (d0 == 0) softpackT<true>(sA, l31, l5, slA, pA);
        else         softpackT<false>(sA, l31, l5, slA, pA);
      }
      if (d0 == -1) softpackT<true>(sB, l31, l5, slB, pB);
      else          softpackT<false>(sB, l31, l5, slB, pB);

      // ---- O^T += V^T P^T, V frag shared across both q-subhalves ----
#pragma unroll
      for (int kp = 0; kp < 2; ++kp) {
        bf16x8 v0 = asbf(*(const u16x8*)&bufp[vfro[kp]]);
        bf16x8 v1 = asbf(*(const u16x8*)&bufp[vfro[kp] + 2048]);
        if (act0) {
          oA0 = __builtin_amdgcn_mfma_f32_32x32x16_bf16(v0, pA[kp], oA0, 0, 0, 0);
          oA1 = __builtin_amdgcn_mfma_f32_32x32x16_bf16(v1, pA[kp], oA1, 0, 0, 0);
        }
        oB0 = __builtin_amdgcn_mfma_f32_32x32x16_bf16(v0, pB[kp], oB0, 0, 0, 0);
        oB1 = __builtin_amdgcn_mfma_f32_32x32x16_bf16(v1, pB[kp], oB1, 0, 0, 0);
      }
    }
    __builtin_amdgcn_s_barrier();       // all waves done reading buf p
  }

  // ---- epilogue: combine l5 halves, park th=0, th=1 combines & stores ----
  float slA2 = slA + __shfl_xor(slA, 32);
  float slB2 = slB + __shfl_xor(slB, 32);
  __syncthreads();
  float* PK = (float*)RAW;              // [128 q][65] f32 (pad breaks conflicts)
  if (th == 0) {
#pragma unroll
    for (int r = 0; r < 16; ++r) {
      const int d = (r & 3) + 8 * (r >> 2) + 4 * l5;
      PK[(qh * 64 + l31) * 65 + d]           = oA0[r];
      PK[(qh * 64 + l31) * 65 + 32 + d]      = oA1[r];
      PK[(qh * 64 + 32 + l31) * 65 + d]      = oB0[r];
      PK[(qh * 64 + 32 + l31) * 65 + 32 + d] = oB1[r];
    }
    PLs[qh * 64 + l31] = slA2;
    PLs[qh * 64 + 32 + l31] = slB2;
  }
  __syncthreads();
  if (th == 1) {
#pragma unroll
    for (int r = 0; r < 16; ++r) {
      const int d = (r & 3) + 8 * (r >> 2) + 4 * l5;
      oA0[r] += PK[(qh * 64 + l31) * 65 + d];
      oA1[r] += PK[(qh * 64 + l31) * 65 + 32 + d];
      oB0[r] += PK[(qh * 64 + 32 + l31) * 65 + d];
      oB1[r] += PK[(qh * 64 + 32 + l31) * 65 + 32 + d];
    }
    const float invA = 1.f / (slA2 + PLs[qh * 64 + l31]);
    const float invB = 1.f / (slB2 + PLs[qh * 64 + 32 + l31]);
#pragma unroll
    for (int s = 0; s < 2; ++s) {
      const f32x16& x0 = s ? oB0 : oA0;
      const f32x16& x1 = s ? oB1 : oA1;
      const float inv = s ? invB : invA;
      const int qg = s ? qgB : qgA;
      u16* yrow = Y + (size_t)(b * NT + qg) * NC + h * 64;
#pragma unroll
      for (int dh = 0; dh < 2; ++dh) {
        const f32x16& o = dh ? x1 : x0;
#pragma unroll
        for (int rq = 0; rq < 4; ++rq) {
          const int d = dh * 32 + 8 * rq + 4 * l5;
          uint2 w;
          w.x = pkbf(o[rq * 4 + 0] * inv, o[rq * 4 + 1] * inv);
          w.y = pkbf(o[rq * 4 + 2] * inv, o[rq * 4 + 3] * inv);
          *(uint2*)&yrow[d] = w;
        }
      }
    }
  }
}

extern "C" void kernel_launch(void* const* d_in, const int* in_sizes, int n_in,
                              void* d_out, int out_size, void* d_ws, size_t ws_size,
                              hipStream_t stream) {
  (void)in_sizes; (void)n_in; (void)out_size; (void)ws_size;
  const float* x = (const float*)d_in[0];
  const float* w_qkv = (const float*)d_in[1];
  const float* w_out = (const float*)d_in[2];
  float* out = (float*)d_out;

  u16* ws = (u16*)d_ws;
  const size_t XE = (size_t)NB * NT * NC;       // 6291456 elements
  u16* xb  = ws;
  u16* wqT = xb + XE;
  u16* woT = wqT + (size_t)3 * NC * NC;
  u16* Qb  = woT + (size_t)NC * NC;
  u16* Kb  = Qb + XE;
  u16* Vtb = Kb + XE;
  u16* yb  = Vtb + XE;

  k_cast<<<(int)(XE / 4 / 256), 256, 0, stream>>>(x, xb, (int)(XE / 4));
  k_transpose<<<dim3(3 * NC / 32, NC / 32), 256, 0, stream>>>(w_qkv, wqT, NC, 3 * NC);
  k_transpose<<<dim3(NC / 32, NC / 32), 256, 0, stream>>>(w_out, woT, NC, NC);
  k_gemm_bt<1><<<dim3(3 * NC / 128, NB * NT / 128), 256, 0, stream>>>(
      xb, wqT, NB * NT, 3 * NC, NC, Qb, Kb, Vtb, nullptr);
  k_attn<<<dim3(768), 256, 0, stream>>>(Qb, Kb, Vtb, yb);
  k_gemm_bt<0><<<dim3(NC / 128, NB * NT / 128), 256, 0, stream>>>(
      yb, woT, NB * NT, NC, NC, nullptr, nullptr, nullptr, out);
}

// Round 4
// 285.868 us; speedup vs baseline: 1.0114x; 1.0114x over previous
//
#include <hip/hip_runtime.h>
#include <stdint.h>
#include <stddef.h>

#define NB 2
#define NT 4096
#define NC 768
#define NH 12
#define ND 64

typedef unsigned short u16;
typedef __attribute__((ext_vector_type(4))) float f32x4;
typedef __attribute__((ext_vector_type(16))) float f32x16;
typedef __attribute__((ext_vector_type(8))) unsigned short u16x8;
typedef __attribute__((ext_vector_type(4))) unsigned short u16x4;
typedef __attribute__((ext_vector_type(8))) __bf16 bf16x8;
typedef __attribute__((ext_vector_type(4))) unsigned int u32x4;

typedef __attribute__((address_space(1))) const unsigned int gu32;
typedef __attribute__((address_space(3))) unsigned int lu32;

__device__ __forceinline__ u16 f2bf(float f) {
  uint32_t u = __builtin_bit_cast(uint32_t, f);
  u += 0x7FFFu + ((u >> 16) & 1u);   // RTNE
  return (u16)(u >> 16);
}
__device__ __forceinline__ bf16x8 asbf(u16x8 v) { return __builtin_bit_cast(bf16x8, v); }

// pack two f32 -> two bf16, round-half-up: 3 VALU
__device__ __forceinline__ uint32_t pkbf(float a, float b) {
  uint32_t ua = __builtin_bit_cast(uint32_t, a) + 0x8000u;
  uint32_t ub = __builtin_bit_cast(uint32_t, b) + 0x8000u;
  return __builtin_amdgcn_perm(ub, ua, 0x07060302u);
}
// truncating pack (P only; numerator/denominator stay consistent): 1 VALU
__device__ __forceinline__ uint32_t pktr(float a, float b) {
  return __builtin_amdgcn_perm(__builtin_bit_cast(uint32_t, b),
                               __builtin_bit_cast(uint32_t, a), 0x07060302u);
}

// ---------------- cast fp32 -> bf16 ----------------
__global__ void k_cast(const float* __restrict__ in, u16* __restrict__ out, int n4) {
  int i = blockIdx.x * blockDim.x + threadIdx.x;
  if (i < n4) {
    f32x4 v = ((const f32x4*)in)[i];
    u16x4 o;
    o[0] = f2bf(v[0]); o[1] = f2bf(v[1]); o[2] = f2bf(v[2]); o[3] = f2bf(v[3]);
    ((u16x4*)out)[i] = o;
  }
}

// -------- transpose + cast --------
__global__ void k_transpose(const float* __restrict__ in, u16* __restrict__ out,
                            int R, int Cn) {
  __shared__ float tile[32][33];
  int c0 = blockIdx.x * 32, r0 = blockIdx.y * 32;
  int tx = threadIdx.x & 31, ty = threadIdx.x >> 5;
  for (int i = ty; i < 32; i += 8)
    tile[i][tx] = in[(size_t)(r0 + i) * Cn + c0 + tx];
  __syncthreads();
  for (int i = ty; i < 32; i += 8)
    out[(size_t)(c0 + i) * R + r0 + tx] = f2bf(tile[tx][i]);
}

// -------- GEMM: C[M,N] = A[M,K] * Bt[N,K]^T --------
template <int EPI>
__global__ __launch_bounds__(256, 2)
void k_gemm_bt(const u16* __restrict__ A, const u16* __restrict__ Bt,
               int M, int N, int K,
               u16* __restrict__ o0, u16* __restrict__ o1, u16* __restrict__ o2,
               float* __restrict__ of) {
  __shared__ u16 As[128 * 40];
  __shared__ u16 Bs[128 * 40];
  const int tid = threadIdx.x;
  const int wave = tid >> 6, lane = tid & 63, quad = lane >> 4, lc = lane & 15;
  const int wm = (wave & 1) * 64, wn = (wave >> 1) * 64;
  const int bm = blockIdx.y * 128, bn = blockIdx.x * 128;

  const int sr = tid >> 2;
  const int sc8 = (tid & 3) * 8;
  const u16* ap0 = A + (size_t)(bm + sr) * K + sc8;
  const u16* ap1 = A + (size_t)(bm + 64 + sr) * K + sc8;
  const u16* bp0 = Bt + (size_t)(bn + sr) * K + sc8;
  const u16* bp1 = Bt + (size_t)(bn + 64 + sr) * K + sc8;
  u16* asl0 = &As[sr * 40 + sc8];
  u16* asl1 = &As[(64 + sr) * 40 + sc8];
  u16* bsl0 = &Bs[sr * 40 + sc8];
  u16* bsl1 = &Bs[(64 + sr) * 40 + sc8];

  f32x4 zv = {0.f, 0.f, 0.f, 0.f};
  f32x4 acc[4][4];
#pragma unroll
  for (int i = 0; i < 4; ++i)
#pragma unroll
    for (int j = 0; j < 4; ++j) acc[i][j] = zv;

  for (int k0 = 0; k0 < K; k0 += 32) {
    u16x8 a0 = *(const u16x8*)(ap0 + k0);
    u16x8 a1 = *(const u16x8*)(ap1 + k0);
    u16x8 b0 = *(const u16x8*)(bp0 + k0);
    u16x8 b1 = *(const u16x8*)(bp1 + k0);
    __syncthreads();
    *(u16x8*)asl0 = a0;
    *(u16x8*)asl1 = a1;
    *(u16x8*)bsl0 = b0;
    *(u16x8*)bsl1 = b1;
    __syncthreads();

    bf16x8 af[4], bfv[4];
#pragma unroll
    for (int mi = 0; mi < 4; ++mi)
      af[mi] = asbf(*(const u16x8*)&As[(wm + mi * 16 + lc) * 40 + quad * 8]);
#pragma unroll
    for (int ni = 0; ni < 4; ++ni)
      bfv[ni] = asbf(*(const u16x8*)&Bs[(wn + ni * 16 + lc) * 40 + quad * 8]);
#pragma unroll
    for (int mi = 0; mi < 4; ++mi)
#pragma unroll
      for (int ni = 0; ni < 4; ++ni)
        acc[mi][ni] = __builtin_amdgcn_mfma_f32_16x16x32_bf16(af[mi], bfv[ni],
                                                              acc[mi][ni], 0, 0, 0);
  }

  const int mrow0 = bm + wm + quad * 4;
#pragma unroll
  for (int mi = 0; mi < 4; ++mi) {
    const int mbase = mrow0 + mi * 16;
#pragma unroll
    for (int ni = 0; ni < 4; ++ni) {
      const int n = bn + wn + ni * 16 + lc;
      if (EPI == 0) {
#pragma unroll
        for (int r = 0; r < 4; ++r)
          of[(size_t)(mbase + r) * N + n] = acc[mi][ni][r];
      } else {
        const int sect = n / NC;          // 0=q 1=k 2=v
        const int wn2 = n - sect * NC;
        const int h = wn2 >> 6, d = wn2 & 63;
        const int b = mbase >> 12;
        const int t = mbase & (NT - 1);
        const float sc = (sect == 0) ? 0.18033688011112042f : 1.0f;  // log2e/8
        if (sect == 2) {
          u16x4 pk;
#pragma unroll
          for (int r = 0; r < 4; ++r) pk[r] = f2bf(acc[mi][ni][r]);
          *(u16x4*)&o2[((size_t)(b * NH + h) * ND + d) * NT + t] = pk;
        } else {
          u16* dst = (sect == 0) ? o0 : o1;
#pragma unroll
          for (int r = 0; r < 4; ++r)
            dst[((size_t)(b * NH + h) * NT + (t + r)) * ND + d] =
                f2bf(acc[mi][ni][r] * sc);
        }
      }
    }
  }
}

// ====== flash attention v4: dual-tile perfect balance + wave-split + DMA ====
// Grid 768 = 24 bh x 32 pairs = exactly 3 blocks/CU; EVERY block does the
// identical 65 tile-units of work: q-tile A = pair (64 rows, active tau<=pair)
// + q-tile B = 63-pair (64 rows, active all tau < ntau = 64-pair).  r0's
// balancing without r1's register blowup: A/B lives at block scope, waves stay
// (qh,th) 2x2 over 64q x 64t, so per-wave state = r3's proven 84-VGPR profile.
// K/V fragments are read ONCE per wave per tau and feed BOTH A and B QK/PV
// (8 ds_reads -> up to 16 MFMAs).  Staging via global_load_lds double buffer
// (linear dest + inverse-XOR-swizzled source, T21), counted vmcnt(4) + raw
// s_barrier (no drain-to-0 in the loop).  P in registers via pktr +
// permlane32_swap; denominator = in-lane truncated-exp sum (bf16-consistent)
// + shfl_xor(32) + cross-th LDS park.  s_setprio(1) wraps MFMA clusters (T5).

template <bool MSK>
__device__ __forceinline__ void softpackT(const f32x16& s, int l31, int l5,
                                          float& sl, bf16x8* pf) {
  float e[16];
#pragma unroll
  for (int r = 0; r < 16; ++r) {
    float v = s[r];
    if (MSK) {
      int tl = (r & 3) + 8 * (r >> 2) + 4 * l5;   // 32x32 C-layout row (t)
      v = (tl > l31) ? -1e30f : v;
    }
    e[r] = exp2f(v);
    sl += __builtin_bit_cast(float,
          __builtin_bit_cast(uint32_t, e[r]) & 0xFFFF0000u);
  }
  uint32_t wv[8];
#pragma unroll
  for (int i = 0; i < 8; ++i) wv[i] = pktr(e[2 * i], e[2 * i + 1]);
#pragma unroll
  for (int g = 0; g < 2; ++g) {
    auto r0 = __builtin_amdgcn_permlane32_swap(wv[g * 4 + 0], wv[g * 4 + 2], false, false);
    auto r1 = __builtin_amdgcn_permlane32_swap(wv[g * 4 + 1], wv[g * 4 + 3], false, false);
    u32x4 f = {r0[0], r1[0], r0[1], r1[1]};
    pf[g] = __builtin_bit_cast(bf16x8, f);
  }
}

#define GLDS(gsrc, ldst) __builtin_amdgcn_global_load_lds( \
    (gu32*)(gsrc), (lu32*)(ldst), 16, 0, 0)

__global__ __launch_bounds__(256, 3)
void k_attn(const u16* __restrict__ Q, const u16* __restrict__ K,
            const u16* __restrict__ Vt, u16* __restrict__ Y) {
  // dbuf staging: buf p at RAW[p*8192]: K tile [64t][64d] elems 0..4095,
  // V^T tile [64d][64t] elems 4096..8191. Epilogue park overlays (128x65 f32).
  __shared__ u16 RAW[2 * 8192 + 768];
  __shared__ float PLs[128];
  const int tid = threadIdx.x;
  const int lane = tid & 63, wave = tid >> 6;
  const int l5 = lane >> 5, l31 = lane & 31;
  const int qh = wave & 1, th = wave >> 1;
  const int o_ = blockIdx.x;
  const int bh = o_ >> 5, pair = o_ & 31;
  const int b = bh / NH, h = bh - b * NH;
  const u16* __restrict__ Qb = Q + (size_t)bh * NT * ND;
  const u16* __restrict__ Kb = K + (size_t)bh * NT * ND;
  const u16* __restrict__ Vb = Vt + (size_t)bh * (size_t)ND * NT;

  const int qA0 = pair * 64, qB0 = (63 - pair) * 64;
  const int ntau = 64 - pair;
  const int dA = pair, dB = ntau - 1;        // diagonal taus for A and B

  // Q as B-operand frags (col q = l31, k(d) = ks*16 + l5*8 + j); log2e/8 folded
  const int qgA = qA0 + qh * 32 + l31;
  const int qgB = qB0 + qh * 32 + l31;
  bf16x8 bqA[4], bqB[4];
#pragma unroll
  for (int ks = 0; ks < 4; ++ks) {
    bqA[ks] = asbf(*(const u16x8*)(Qb + (size_t)qgA * ND + ks * 16 + l5 * 8));
    bqB[ks] = asbf(*(const u16x8*)(Qb + (size_t)qgB * ND + ks * 16 + l5 * 8));
  }

  f32x16 Zv;
#pragma unroll
  for (int i = 0; i < 16; ++i) Zv[i] = 0.f;
  f32x16 oA0 = Zv, oA1 = Zv, oB0 = Zv, oB1 = Zv;   // O^T partials, d-halves
  float slA = 0.f, slB = 0.f;

  // DMA staging: wave w stages LDS rows [16w,16w+16) of K and of V.
  // LDS element off = row*64 + (g ^ (row&7))*8 ; DMA writes linear
  // (lane c -> row + c/8, granule c%8), so the SOURCE granule is pre-swizzled.
  const int lr = lane >> 3;                       // 0..7
  const int gsw = ((lane & 7) ^ lr) * 8;          // inverse-swizzled granule
  const int r0w = wave * 16;
  const u16* gk0 = Kb + (size_t)(r0w + lr) * ND + gsw;       // + t0*ND
  const u16* gk1 = gk0 + (size_t)8 * ND;
  const u16* gv0 = Vb + (size_t)(r0w + lr) * NT + gsw;       // + t0
  const u16* gv1 = gv0 + (size_t)8 * NT;
  u16* lk0 = &RAW[r0w * 64];
  u16* lv0 = &RAW[4096 + r0w * 64];

  // frag read offsets (elements) within a buffer
  int qfro[4];
#pragma unroll
  for (int ks = 0; ks < 4; ++ks)
    qfro[ks] = (th * 32 + l31) * 64 + (((ks * 2 + l5) ^ (l31 & 7)) * 8);
  int vfro[2];
#pragma unroll
  for (int kp = 0; kp < 2; ++kp)
    vfro[kp] = 4096 + l31 * 64 + (((4 * th + 2 * kp + l5) ^ (l31 & 7)) * 8);

  // prologue: DMA tile 0 into buf 0
  GLDS(gk0, lk0);
  GLDS(gk1, lk0 + 512);
  GLDS(gv0, lv0);
  GLDS(gv1, lv0 + 512);

#pragma unroll 1
  for (int tau = 0; tau < ntau; ++tau) {
    const int p = tau & 1;
    if (tau + 1 < ntau) {               // issue next tile into other buf
      const int tn = (tau + 1) * 64;
      const int bo = (p ^ 1) * 8192;
      GLDS(gk0 + (size_t)tn * ND, lk0 + bo);
      GLDS(gk1 + (size_t)tn * ND, lk0 + bo + 512);
      GLDS(gv0 + tn, lv0 + bo);
      GLDS(gv1 + tn, lv0 + bo + 512);
      asm volatile("s_waitcnt vmcnt(4)" ::: "memory");  // current tile landed
    } else {
      asm volatile("s_waitcnt vmcnt(0)" ::: "memory");
    }
    __builtin_amdgcn_s_barrier();       // all waves' tile-tau DMA complete

    // wave activity for each q-tile this tau (block-uniform per wave)
    const bool aA = (tau < dA) || (tau == dA && th <= qh);
    const bool mA = (tau == dA) && (th == qh);
    const bool aB = (tau < dB) || (th <= qh);
    const bool mB = (tau == dB) && (th == qh);

    if (aA || aB) {
      const u16* bufp = &RAW[p * 8192];

      // ---- S^T = K Q^T ; each K frag feeds both A and B ----
      f32x16 sA = Zv, sB = Zv;
      __builtin_amdgcn_s_setprio(1);
#pragma unroll
      for (int ks = 0; ks < 4; ++ks) {
        bf16x8 kf = asbf(*(const u16x8*)&bufp[qfro[ks]]);
        if (aA)
          sA = __builtin_amdgcn_mfma_f32_32x32x16_bf16(kf, bqA[ks], sA, 0, 0, 0);
        if (aB)
          sB = __builtin_amdgcn_mfma_f32_32x32x16_bf16(kf, bqB[ks], sB, 0, 0, 0);
      }
      __builtin_amdgcn_s_setprio(0);

      // ---- softmax numerators in-register ----
      bf16x8 pA[2], pB[2];
      if (aA) {
        if (mA) softpackT<true>(sA, l31, l5, slA, pA);
        else    softpackT<false>(sA, l31, l5, slA, pA);
      }
      if (aB) {
        if (mB) softpackT<true>(sB, l31, l5, slB, pB);
        else    softpackT<false>(sB, l31, l5, slB, pB);
      }

      // ---- O^T += V^T P^T ; each V frag feeds both A and B ----
      __builtin_amdgcn_s_setprio(1);
#pragma unroll
      for (int kp = 0; kp < 2; ++kp) {
        bf16x8 v0 = asbf(*(const u16x8*)&bufp[vfro[kp]]);
        bf16x8 v1 = asbf(*(const u16x8*)&bufp[vfro[kp] + 2048]);
        if (aA) {
          oA0 = __builtin_amdgcn_mfma_f32_32x32x16_bf16(v0, pA[kp], oA0, 0, 0, 0);
          oA1 = __builtin_amdgcn_mfma_f32_32x32x16_bf16(v1, pA[kp], oA1, 0, 0, 0);
        }
        if (aB) {
          oB0 = __builtin_amdgcn_mfma_f32_32x32x16_bf16(v0, pB[kp], oB0, 0, 0, 0);
          oB1 = __builtin_amdgcn_mfma_f32_32x32x16_bf16(v1, pB[kp], oB1, 0, 0, 0);
        }
      }
      __builtin_amdgcn_s_setprio(0);
    }
    __builtin_amdgcn_s_barrier();       // all waves done reading buf p
  }

  // ---- epilogue: combine l5 halves, park th=0, th=1 combines & stores ----
  float slA2 = slA + __shfl_xor(slA, 32);
  float slB2 = slB + __shfl_xor(slB, 32);
  __syncthreads();
  float* PK = (float*)RAW;              // [128 q][65] f32 (pad breaks conflicts)
  const int rA = qh * 32 + l31, rB = 64 + qh * 32 + l31;
  if (th == 0) {
#pragma unroll
    for (int r = 0; r < 16; ++r) {
      const int d = (r & 3) + 8 * (r >> 2) + 4 * l5;
      PK[rA * 65 + d]      = oA0[r];
      PK[rA * 65 + 32 + d] = oA1[r];
      PK[rB * 65 + d]      = oB0[r];
      PK[rB * 65 + 32 + d] = oB1[r];
    }
    PLs[rA] = slA2;
    PLs[rB] = slB2;
  }
  __syncthreads();
  if (th == 1) {
#pragma unroll
    for (int r = 0; r < 16; ++r) {
      const int d = (r & 3) + 8 * (r >> 2) + 4 * l5;
      oA0[r] += PK[rA * 65 + d];
      oA1[r] += PK[rA * 65 + 32 + d];
      oB0[r] += PK[rB * 65 + d];
      oB1[r] += PK[rB * 65 + 32 + d];
    }
    const float invA = 1.f / (slA2 + PLs[rA]);
    const float invB = 1.f / (slB2 + PLs[rB]);
#pragma unroll
    for (int s = 0; s < 2; ++s) {
      const f32x16& x0 = s ? oB0 : oA0;
      const f32x16& x1 = s ? oB1 : oA1;
      const float inv = s ? invB : invA;
      const int qg = s ? qgB : qgA;
      u16* yrow = Y + (size_t)(b * NT + qg) * NC + h * 64;
#pragma unroll
      for (int dh = 0; dh < 2; ++dh) {
        const f32x16& o = dh ? x1 : x0;
#pragma unroll
        for (int rq = 0; rq < 4; ++rq) {
          const int d = dh * 32 + 8 * rq + 4 * l5;
          uint2 w;
          w.x = pkbf(o[rq * 4 + 0] * inv, o[rq * 4 + 1] * inv);
          w.y = pkbf(o[rq * 4 + 2] * inv, o[rq * 4 + 3] * inv);
          *(uint2*)&yrow[d] = w;
        }
      }
    }
  }
}

extern "C" void kernel_launch(void* const* d_in, const int* in_sizes, int n_in,
                              void* d_out, int out_size, void* d_ws, size_t ws_size,
                              hipStream_t stream) {
  (void)in_sizes; (void)n_in; (void)out_size; (void)ws_size;
  const float* x = (const float*)d_in[0];
  const float* w_qkv = (const float*)d_in[1];
  const float* w_out = (const float*)d_in[2];
  float* out = (float*)d_out;

  u16* ws = (u16*)d_ws;
  const size_t XE = (size_t)NB * NT * NC;       // 6291456 elements
  u16* xb  = ws;
  u16* wqT = xb + XE;
  u16* woT = wqT + (size_t)3 * NC * NC;
  u16* Qb  = woT + (size_t)NC * NC;
  u16* Kb  = Qb + XE;
  u16* Vtb = Kb + XE;
  u16* yb  = Vtb + XE;

  k_cast<<<(int)(XE / 4 / 256), 256, 0, stream>>>(x, xb, (int)(XE / 4));
  k_transpose<<<dim3(3 * NC / 32, NC / 32), 256, 0, stream>>>(w_qkv, wqT, NC, 3 * NC);
  k_transpose<<<dim3(NC / 32, NC / 32), 256, 0, stream>>>(w_out, woT, NC, NC);
  k_gemm_bt<1><<<dim3(3 * NC / 128, NB * NT / 128), 256, 0, stream>>>(
      xb, wqT, NB * NT, 3 * NC, NC, Qb, Kb, Vtb, nullptr);
  k_attn<<<dim3(768), 256, 0, stream>>>(Qb, Kb, Vtb, yb);
  k_gemm_bt<0><<<dim3(NC / 128, NB * NT / 128), 256, 0, stream>>>(
      yb, woT, NB * NT, NC, NC, nullptr, nullptr, nullptr, out);
}